// Round 6
// baseline (507.142 us; speedup 1.0000x reference)
//
#include <hip/hip_runtime.h>

typedef _Float16 f16;
typedef _Float16 f16x4 __attribute__((ext_vector_type(4)));
typedef _Float16 f16x8 __attribute__((ext_vector_type(8)));
typedef float f32x4 __attribute__((ext_vector_type(4)));

#define MFMA16(a, b, c) __builtin_amdgcn_mfma_f32_16x16x32_f16(a, b, c, 0, 0, 0)

// ---------------- Kernel 1: per-(tensor,b,c) mean / inv-std ----------------
__global__ __launch_bounds__(256) void stats_kernel(
    const float* __restrict__ content, const float* __restrict__ style,
    float* __restrict__ mu, float* __restrict__ rs)
{
    int bid = blockIdx.x;            // tensor*2048 + b*512 + c
    int tensor = bid >> 11;
    int row = bid & 2047;
    const float* src = (tensor ? style : content) + (size_t)row * 4096;
    int t = threadIdx.x;
    float s = 0.f, ss = 0.f;
    for (int i = t; i < 1024; i += 256) {
        float4 v = reinterpret_cast<const float4*>(src)[i];
        s  += v.x + v.y + v.z + v.w;
        ss += v.x * v.x + v.y * v.y + v.z * v.z + v.w * v.w;
    }
    for (int off = 32; off > 0; off >>= 1) {
        s  += __shfl_down(s, off);
        ss += __shfl_down(ss, off);
    }
    __shared__ float sb[4], ssb[4];
    int wv = t >> 6;
    if ((t & 63) == 0) { sb[wv] = s; ssb[wv] = ss; }
    __syncthreads();
    if (t == 0) {
        float S  = sb[0] + sb[1] + sb[2] + sb[3];
        float SS = ssb[0] + ssb[1] + ssb[2] + ssb[3];
        float m  = S * (1.f / 4096.f);
        float var = (SS - 4096.f * m * m) * (1.f / 4095.f);
        mu[bid] = m;
        rs[bid] = rsqrtf(var + 1e-5f);
    }
}

// ---------------- Kernel 2: fused norm + 1x1-conv (Q,K,V) -----------------
__global__ __launch_bounds__(256) void qkv_kernel(
    const float* __restrict__ content, const float* __restrict__ style,
    const float* __restrict__ Wq, const float* __restrict__ bq,
    const float* __restrict__ Wk, const float* __restrict__ bk,
    const float* __restrict__ Wv, const float* __restrict__ bv,
    const float* __restrict__ mu, const float* __restrict__ rs,
    f16* __restrict__ Qt, f16* __restrict__ Kt, f16* __restrict__ Vc)
{
    int z = blockIdx.z;
    int b = z / 3, p = z % 3;
    int n0 = blockIdx.x * 128;
    int o0 = blockIdx.y * 128;
    const float* X    = (p == 0 ? content : style) + (size_t)b * 512 * 4096;
    const float* W    = (p == 0 ? Wq : (p == 1 ? Wk : Wv));
    const float* bias = (p == 0 ? bq : (p == 1 ? bk : bv));
    const float* muT = mu + (p == 0 ? 0 : 2048) + b * 512;
    const float* rsT = rs + (p == 0 ? 0 : 2048) + b * 512;
    bool norm = (p < 2);

    __shared__ __align__(16) f16 Xt[128][40];
    __shared__ __align__(16) f16 Wl[128][40];

    int t = threadIdx.x;
    int lane = t & 63, w = t >> 6;
    int wn = (w & 1) * 64, wo = (w >> 1) * 64;
    int lg = lane >> 4, li = lane & 15;

    f32x4 acc[4][4];
#pragma unroll
    for (int i = 0; i < 4; ++i)
#pragma unroll
        for (int j = 0; j < 4; ++j)
#pragma unroll
            for (int e = 0; e < 4; ++e) acc[i][j][e] = 0.f;

    for (int kk = 0; kk < 16; ++kk) {
        int c0 = kk * 32;
        __syncthreads();
#pragma unroll
        for (int r = 0; r < 4; ++r) {
            int linear = r * 256 + t;
            int c  = linear >> 5;
            int nq = linear & 31;
            float4 v = reinterpret_cast<const float4*>(X + (size_t)(c0 + c) * 4096 + n0)[nq];
            float m = 0.f, sc = 1.f;
            if (norm) { m = muT[c0 + c]; sc = rsT[c0 + c]; }
            int n = nq * 4;
            Xt[n + 0][c] = (f16)((v.x - m) * sc);
            Xt[n + 1][c] = (f16)((v.y - m) * sc);
            Xt[n + 2][c] = (f16)((v.z - m) * sc);
            Xt[n + 3][c] = (f16)((v.w - m) * sc);
        }
#pragma unroll
        for (int r = 0; r < 4; ++r) {
            int linear = r * 256 + t;
            int o  = linear >> 3;
            int cq = linear & 7;
            float4 v = reinterpret_cast<const float4*>(W + (size_t)(o0 + o) * 512 + c0)[cq];
            int c = cq * 4;
            Wl[o][c + 0] = (f16)v.x;
            Wl[o][c + 1] = (f16)v.y;
            Wl[o][c + 2] = (f16)v.z;
            Wl[o][c + 3] = (f16)v.w;
        }
        __syncthreads();

        f16x8 xf[4], wf[4];
#pragma unroll
        for (int f = 0; f < 4; ++f) {
            xf[f] = *reinterpret_cast<const f16x8*>(&Xt[wn + f * 16 + li][lg * 8]);
            wf[f] = *reinterpret_cast<const f16x8*>(&Wl[wo + f * 16 + li][lg * 8]);
        }
        if (p < 2) {
#pragma unroll
            for (int i = 0; i < 4; ++i)
#pragma unroll
                for (int j = 0; j < 4; ++j)
                    acc[i][j] = MFMA16(xf[i], wf[j], acc[i][j]);
        } else {
#pragma unroll
            for (int i = 0; i < 4; ++i)
#pragma unroll
                for (int j = 0; j < 4; ++j)
                    acc[i][j] = MFMA16(wf[i], xf[j], acc[i][j]);
        }
    }

    if (p < 2) {
        f16* dst = (p == 0 ? Qt : Kt) + (size_t)b * 4096 * 512;
#pragma unroll
        for (int j = 0; j < 4; ++j) {
            int o = o0 + wo + j * 16 + li;
            float bb = bias[o];
#pragma unroll
            for (int i = 0; i < 4; ++i)
#pragma unroll
                for (int e = 0; e < 4; ++e) {
                    int n = n0 + wn + i * 16 + lg * 4 + e;
                    dst[(size_t)n * 512 + o] = (f16)(acc[i][j][e] + bb);
                }
        }
    } else {
#pragma unroll
        for (int i = 0; i < 4; ++i)
#pragma unroll
            for (int e = 0; e < 4; ++e) {
                int o = o0 + wo + i * 16 + lg * 4 + e;
                float bb = bias[o];
#pragma unroll
                for (int j = 0; j < 4; ++j) {
                    int n = n0 + wn + j * 16 + li;
                    Vc[((size_t)b * 512 + o) * 4096 + n] = (f16)(acc[i][j][e] + bb);
                }
            }
    }
}

// ---------------- Kernel 3: flash attention, 6-wave / 2 blocks per CU ------
// 384 thr: waves 0-1 = QK+softmax (16 q-rows each, wave-local stats);
//          waves 2-5 = PV (c-slice 128 each), V direct from L2.
// TQ=32, KVBLK=32, 512 blocks (2/CU), ONE barrier per iteration.
__global__ __launch_bounds__(384, 3) void attn_kernel(
    const f16* __restrict__ Qt, const f16* __restrict__ Kt,
    const f16* __restrict__ Vc, float* __restrict__ out)
{
    int bid = blockIdx.x;
    int orig = (bid & 7) * 64 + (bid >> 3);   // XCD chunking: 64 contiguous per XCD
    int b = orig >> 7;
    int n0 = (orig & 127) * 32;

    int t = threadIdx.x;
    int lane = t & 63, w = t >> 6;
    int lg = lane >> 4, li = lane & 15;

    __shared__ __align__(16) f16 Km[2][32][520];   // K ping-pong [m][c]
    __shared__ __align__(16) f16 Pl[2][32][44];    // P ping-pong [q][m]
    __shared__ __align__(16) float Rrow[2][32];
    __shared__ __align__(16) float Lrow[32];
    __shared__ int Rflag[2][2];

    const f16* Qb = Qt + (size_t)b * 4096 * 512;
    const f16* Kb = Kt + (size_t)b * 4096 * 512;
    const f16* Vb = Vc + (size_t)b * 512 * 4096;

    if (w < 2) {
        // =============== QK / softmax wave (q-half j = w) ===============
        int j = w;
        // Q B-frags pinned: rows n0 + j*16 + li, k = 0..511
        f16x8 qf[16];
#pragma unroll
        for (int kk = 0; kk < 16; ++kk)
            qf[kk] = *reinterpret_cast<const f16x8*>(
                Qb + (size_t)(n0 + j * 16 + li) * 512 + kk * 32 + lg * 8);

#define STAGEK(TILE)                                                           \
        {                                                                      \
            int _db = (TILE) & 1;                                              \
            _Pragma("unroll")                                                  \
            for (int r = 0; r < 16; ++r) {                                     \
                const f16* _gs = Kb + ((size_t)(TILE) * 32 + j * 16 + r) * 512 \
                                 + lane * 8;                                   \
                __builtin_amdgcn_global_load_lds(                              \
                    (const __attribute__((address_space(1))) void*)_gs,        \
                    (__attribute__((address_space(3))) void*)&Km[_db][j * 16 + r][0], \
                    16, 0, 0);                                                 \
            }                                                                  \
        }

        STAGEK(0);
        float Mreg = -3.4e38f, Lreg = 0.f;
        __syncthreads();   // prologue: Km[0] drained by barrier's vmcnt

        for (int it = 0; it <= 128; ++it) {
            if (it <= 127) {
                int cur = it & 1;
                if (it < 127) STAGEK(it + 1);

                // S^T = K*Q : 2 m-tiles x 2 chains, 32 MFMA16
                f32x4 sa0 = {0.f,0.f,0.f,0.f}, sb0 = {0.f,0.f,0.f,0.f};
                f32x4 sa1 = {0.f,0.f,0.f,0.f}, sb1 = {0.f,0.f,0.f,0.f};
                __builtin_amdgcn_s_setprio(1);
#pragma unroll
                for (int kk = 0; kk < 16; kk += 2) {
                    f16x8 a00 = *reinterpret_cast<const f16x8*>(&Km[cur][li][kk * 32 + lg * 8]);
                    f16x8 a10 = *reinterpret_cast<const f16x8*>(&Km[cur][16 + li][kk * 32 + lg * 8]);
                    f16x8 a01 = *reinterpret_cast<const f16x8*>(&Km[cur][li][(kk + 1) * 32 + lg * 8]);
                    f16x8 a11 = *reinterpret_cast<const f16x8*>(&Km[cur][16 + li][(kk + 1) * 32 + lg * 8]);
                    sa0 = MFMA16(a00, qf[kk], sa0);
                    sa1 = MFMA16(a10, qf[kk], sa1);
                    sb0 = MFMA16(a01, qf[kk + 1], sb0);
                    sb1 = MFMA16(a11, qf[kk + 1], sb1);
                }
                __builtin_amdgcn_s_setprio(0);
                f32x4 s0, s1;
#pragma unroll
                for (int e = 0; e < 4; ++e) { s0[e] = sa0[e] + sb0[e]; s1[e] = sa1[e] + sb1[e]; }

                // wave-local online softmax; lane holds m = {lg*4+e, 16+lg*4+e} for q=li
                float mx = fmaxf(fmaxf(fmaxf(s0[0], s0[1]), fmaxf(s0[2], s0[3])),
                                 fmaxf(fmaxf(s1[0], s1[1]), fmaxf(s1[2], s1[3])));
                mx = fmaxf(mx, __shfl_xor(mx, 16));
                mx = fmaxf(mx, __shfl_xor(mx, 32));
                bool needR = (mx - Mreg) > 4.0f;       // defer-max THR=4
                float Mnew = needR ? mx : Mreg;
                float r = needR ? __expf(Mreg - Mnew) : 1.f;
                float p0[4], p1[4];
                float sum = 0.f;
#pragma unroll
                for (int e = 0; e < 4; ++e) {
                    p0[e] = __expf(s0[e] - Mnew);
                    p1[e] = __expf(s1[e] - Mnew);
                    sum += p0[e] + p1[e];
                }
                sum += __shfl_xor(sum, 16);
                sum += __shfl_xor(sum, 32);
                Lreg = Lreg * r + sum;
                Mreg = Mnew;

                f16x4 pk0, pk1;
#pragma unroll
                for (int e = 0; e < 4; ++e) { pk0[e] = (f16)p0[e]; pk1[e] = (f16)p1[e]; }
                *reinterpret_cast<f16x4*>(&Pl[cur][j * 16 + li][lg * 4])      = pk0;
                *reinterpret_cast<f16x4*>(&Pl[cur][j * 16 + li][16 + lg * 4]) = pk1;
                if (lg == 0) Rrow[cur][j * 16 + li] = r;
                int any = __any(needR);
                if (lane == 0) Rflag[cur][j] = any;
                if (it == 127 && lg == 0) Lrow[j * 16 + li] = Lreg;
            }
            __syncthreads();
        }
#undef STAGEK
    } else {
        // =============== PV wave (c-slice 128) ===============
        int pw = w - 2;
        int c0 = pw * 128;
        f32x4 acc[2][8];
#pragma unroll
        for (int fn = 0; fn < 2; ++fn)
#pragma unroll
            for (int fc = 0; fc < 8; ++fc)
#pragma unroll
                for (int e = 0; e < 4; ++e) acc[fn][fc][e] = 0.f;
        f16x8 vfr[8];   // V B-frags for tile it (loaded end of iter it)

        __syncthreads();   // prologue barrier

        for (int it = 0; it <= 128; ++it) {
            if (it >= 1) {
                int pp = (it - 1) & 1;
                if (Rflag[pp][0] | Rflag[pp][1]) {
#pragma unroll
                    for (int fn = 0; fn < 2; ++fn) {
                        f32x4 rv = *reinterpret_cast<const f32x4*>(&Rrow[pp][fn * 16 + lg * 4]);
#pragma unroll
                        for (int fc = 0; fc < 8; ++fc)
#pragma unroll
                            for (int e = 0; e < 4; ++e) acc[fn][fc][e] *= rv[e];
                    }
                }
                __builtin_amdgcn_s_setprio(1);
#pragma unroll
                for (int fn = 0; fn < 2; ++fn) {
                    f16x8 af = *reinterpret_cast<const f16x8*>(&Pl[pp][fn * 16 + li][lg * 8]);
#pragma unroll
                    for (int fc = 0; fc < 8; ++fc)
                        acc[fn][fc] = MFMA16(af, vfr[fc], acc[fn][fc]);
                }
                __builtin_amdgcn_s_setprio(0);
            }
            if (it < 128) {
                // load V(it), consumed next iteration
                const f16* vs = Vb + (size_t)(c0 + li) * 4096 + it * 32 + lg * 8;
#pragma unroll
                for (int fc = 0; fc < 8; ++fc)
                    vfr[fc] = *reinterpret_cast<const f16x8*>(vs + (size_t)fc * 16 * 4096);
            }
            __syncthreads();
        }

        // epilogue: divide by L, store out[b][c][n]
        float* ob = out + (size_t)b * 512 * 4096;
#pragma unroll
        for (int fn = 0; fn < 2; ++fn) {
            f32x4 lv = *reinterpret_cast<const f32x4*>(&Lrow[fn * 16 + lg * 4]);
            f32x4 linv;
#pragma unroll
            for (int e = 0; e < 4; ++e) linv[e] = 1.f / lv[e];
#pragma unroll
            for (int fc = 0; fc < 8; ++fc) {
                int c = c0 + fc * 16 + li;
                f32x4 o4;
#pragma unroll
                for (int e = 0; e < 4; ++e) o4[e] = acc[fn][fc][e] * linv[e];
                *reinterpret_cast<f32x4*>(ob + (size_t)c * 4096 + n0 + fn * 16 + lg * 4) = o4;
            }
        }
    }
}

// ---------------------------------------------------------------------------
extern "C" void kernel_launch(void* const* d_in, const int* in_sizes, int n_in,
                              void* d_out, int out_size, void* d_ws, size_t ws_size,
                              hipStream_t stream)
{
    const float* content = (const float*)d_in[0];
    const float* style   = (const float*)d_in[1];
    const float* Wq = (const float*)d_in[2];
    const float* bq = (const float*)d_in[3];
    const float* Wk = (const float*)d_in[4];
    const float* bk = (const float*)d_in[5];
    const float* Wv = (const float*)d_in[6];
    const float* bv = (const float*)d_in[7];
    float* out = (float*)d_out;

    const size_t TEN = (size_t)4 * 4096 * 512;
    f16* Qt = (f16*)d_ws;
    f16* Kt = Qt + TEN;
    f16* Vc = Kt + TEN;
    float* mu = (float*)(Vc + TEN);
    float* rs = mu + 4096;

    hipLaunchKernelGGL(stats_kernel, dim3(4096), dim3(256), 0, stream,
                       content, style, mu, rs);
    hipLaunchKernelGGL(qkv_kernel, dim3(32, 4, 12), dim3(256), 0, stream,
                       content, style, Wq, bq, Wk, bk, Wv, bv, mu, rs, Qt, Kt, Vc);
    hipLaunchKernelGGL(attn_kernel, dim3(512), dim3(384), 0, stream,
                       Qt, Kt, Vc, out);
}

// Round 7
// 330.062 us; speedup vs baseline: 1.5365x; 1.5365x over previous
//
#include <hip/hip_runtime.h>

typedef _Float16 f16;
typedef _Float16 f16x4 __attribute__((ext_vector_type(4)));
typedef _Float16 f16x8 __attribute__((ext_vector_type(8)));
typedef float f32x4 __attribute__((ext_vector_type(4)));

#define MFMA16(a, b, c) __builtin_amdgcn_mfma_f32_16x16x32_f16(a, b, c, 0, 0, 0)

// ---------------- Kernel 1: per-(tensor,b,c) mean / inv-std ----------------
__global__ __launch_bounds__(256) void stats_kernel(
    const float* __restrict__ content, const float* __restrict__ style,
    float* __restrict__ mu, float* __restrict__ rs)
{
    int bid = blockIdx.x;            // tensor*2048 + b*512 + c
    int tensor = bid >> 11;
    int row = bid & 2047;
    const float* src = (tensor ? style : content) + (size_t)row * 4096;
    int t = threadIdx.x;
    float s = 0.f, ss = 0.f;
    for (int i = t; i < 1024; i += 256) {
        float4 v = reinterpret_cast<const float4*>(src)[i];
        s  += v.x + v.y + v.z + v.w;
        ss += v.x * v.x + v.y * v.y + v.z * v.z + v.w * v.w;
    }
    for (int off = 32; off > 0; off >>= 1) {
        s  += __shfl_down(s, off);
        ss += __shfl_down(ss, off);
    }
    __shared__ float sb[4], ssb[4];
    int wv = t >> 6;
    if ((t & 63) == 0) { sb[wv] = s; ssb[wv] = ss; }
    __syncthreads();
    if (t == 0) {
        float S  = sb[0] + sb[1] + sb[2] + sb[3];
        float SS = ssb[0] + ssb[1] + ssb[2] + ssb[3];
        float m  = S * (1.f / 4096.f);
        float var = (SS - 4096.f * m * m) * (1.f / 4095.f);
        mu[bid] = m;
        rs[bid] = rsqrtf(var + 1e-5f);
    }
}

// ---------------- Kernel 2: fused norm + 1x1-conv (Q,K,V) -----------------
__global__ __launch_bounds__(256) void qkv_kernel(
    const float* __restrict__ content, const float* __restrict__ style,
    const float* __restrict__ Wq, const float* __restrict__ bq,
    const float* __restrict__ Wk, const float* __restrict__ bk,
    const float* __restrict__ Wv, const float* __restrict__ bv,
    const float* __restrict__ mu, const float* __restrict__ rs,
    f16* __restrict__ Qt, f16* __restrict__ Kt, f16* __restrict__ Vc)
{
    int z = blockIdx.z;
    int b = z / 3, p = z % 3;
    int n0 = blockIdx.x * 128;
    int o0 = blockIdx.y * 128;
    const float* X    = (p == 0 ? content : style) + (size_t)b * 512 * 4096;
    const float* W    = (p == 0 ? Wq : (p == 1 ? Wk : Wv));
    const float* bias = (p == 0 ? bq : (p == 1 ? bk : bv));
    const float* muT = mu + (p == 0 ? 0 : 2048) + b * 512;
    const float* rsT = rs + (p == 0 ? 0 : 2048) + b * 512;
    bool norm = (p < 2);

    __shared__ __align__(16) f16 Xt[128][40];
    __shared__ __align__(16) f16 Wl[128][40];

    int t = threadIdx.x;
    int lane = t & 63, w = t >> 6;
    int wn = (w & 1) * 64, wo = (w >> 1) * 64;
    int lg = lane >> 4, li = lane & 15;

    f32x4 acc[4][4];
#pragma unroll
    for (int i = 0; i < 4; ++i)
#pragma unroll
        for (int j = 0; j < 4; ++j)
#pragma unroll
            for (int e = 0; e < 4; ++e) acc[i][j][e] = 0.f;

    for (int kk = 0; kk < 16; ++kk) {
        int c0 = kk * 32;
        __syncthreads();
#pragma unroll
        for (int r = 0; r < 4; ++r) {
            int linear = r * 256 + t;
            int c  = linear >> 5;
            int nq = linear & 31;
            float4 v = reinterpret_cast<const float4*>(X + (size_t)(c0 + c) * 4096 + n0)[nq];
            float m = 0.f, sc = 1.f;
            if (norm) { m = muT[c0 + c]; sc = rsT[c0 + c]; }
            int n = nq * 4;
            Xt[n + 0][c] = (f16)((v.x - m) * sc);
            Xt[n + 1][c] = (f16)((v.y - m) * sc);
            Xt[n + 2][c] = (f16)((v.z - m) * sc);
            Xt[n + 3][c] = (f16)((v.w - m) * sc);
        }
#pragma unroll
        for (int r = 0; r < 4; ++r) {
            int linear = r * 256 + t;
            int o  = linear >> 3;
            int cq = linear & 7;
            float4 v = reinterpret_cast<const float4*>(W + (size_t)(o0 + o) * 512 + c0)[cq];
            int c = cq * 4;
            Wl[o][c + 0] = (f16)v.x;
            Wl[o][c + 1] = (f16)v.y;
            Wl[o][c + 2] = (f16)v.z;
            Wl[o][c + 3] = (f16)v.w;
        }
        __syncthreads();

        f16x8 xf[4], wf[4];
#pragma unroll
        for (int f = 0; f < 4; ++f) {
            xf[f] = *reinterpret_cast<const f16x8*>(&Xt[wn + f * 16 + li][lg * 8]);
            wf[f] = *reinterpret_cast<const f16x8*>(&Wl[wo + f * 16 + li][lg * 8]);
        }
        if (p < 2) {
#pragma unroll
            for (int i = 0; i < 4; ++i)
#pragma unroll
                for (int j = 0; j < 4; ++j)
                    acc[i][j] = MFMA16(xf[i], wf[j], acc[i][j]);
        } else {
#pragma unroll
            for (int i = 0; i < 4; ++i)
#pragma unroll
                for (int j = 0; j < 4; ++j)
                    acc[i][j] = MFMA16(wf[i], xf[j], acc[i][j]);
        }
    }

    if (p < 2) {
        f16* dst = (p == 0 ? Qt : Kt) + (size_t)b * 4096 * 512;
#pragma unroll
        for (int j = 0; j < 4; ++j) {
            int o = o0 + wo + j * 16 + li;
            float bb = bias[o];
#pragma unroll
            for (int i = 0; i < 4; ++i)
#pragma unroll
                for (int e = 0; e < 4; ++e) {
                    int n = n0 + wn + i * 16 + lg * 4 + e;
                    dst[(size_t)n * 512 + o] = (f16)(acc[i][j][e] + bb);
                }
        }
    } else {
#pragma unroll
        for (int i = 0; i < 4; ++i)
#pragma unroll
            for (int e = 0; e < 4; ++e) {
                int o = o0 + wo + i * 16 + lg * 4 + e;
                float bb = bias[o];
#pragma unroll
                for (int j = 0; j < 4; ++j) {
                    int n = n0 + wn + j * 16 + li;
                    Vc[((size_t)b * 512 + o) * 4096 + n] = (f16)(acc[i][j][e] + bb);
                }
            }
    }
}

// ---------------- Kernel 3: flash attention, 12-wave balanced --------------
// 768 thr = 12 waves; SIMD k hosts waves {k, k+4, k+8} = 1 QK + 2 PV.
// Waves 0-3: QK (16 q-rows each, wave-local softmax via swapped mfma(K,Q)).
// Waves 4-11: PV (64 c each), V in registers, P via LDS ping-pong.
// TQ=64, KVBLK=32, grid 256 (1 block/CU), ONE barrier per iteration.
__global__ __launch_bounds__(768, 3) void attn_kernel(
    const f16* __restrict__ Qt, const f16* __restrict__ Kt,
    const f16* __restrict__ Vc, float* __restrict__ out)
{
    int bid = blockIdx.x;
    int orig = (bid & 7) * 32 + (bid >> 3);   // XCD chunking
    int b = orig >> 6;
    int n0 = (orig & 63) * 64;

    int t = threadIdx.x;
    int lane = t & 63, w = t >> 6;
    int lg = lane >> 4, li = lane & 15;

    __shared__ __align__(16) f16 Km[2][32][520];   // K dbuf [m][c]
    __shared__ __align__(16) f16 Pl[2][64][40];    // P ping-pong [q][m]
    __shared__ __align__(16) float Rrow[2][64];
    __shared__ __align__(16) float Lrow[64];
    __shared__ int Rflag[2][4];

    const f16* Qb = Qt + (size_t)b * 4096 * 512;
    const f16* Kb = Kt + (size_t)b * 4096 * 512;
    const f16* Vb = Vc + (size_t)b * 512 * 4096;

    if (w < 4) {
        // =============== QK / softmax wave j = w (q-rows n0+j*16..+16) =====
        int j = w;
        f16x8 qf[16];
#pragma unroll
        for (int kk = 0; kk < 16; ++kk)
            qf[kk] = *reinterpret_cast<const f16x8*>(
                Qb + (size_t)(n0 + j * 16 + li) * 512 + kk * 32 + lg * 8);

#define STAGEK(TILE)                                                           \
        {                                                                      \
            int _db = (TILE) & 1;                                              \
            _Pragma("unroll")                                                  \
            for (int r = 0; r < 8; ++r) {                                      \
                const f16* _gs = Kb + ((size_t)(TILE) * 32 + j * 8 + r) * 512  \
                                 + lane * 8;                                   \
                __builtin_amdgcn_global_load_lds(                              \
                    (const __attribute__((address_space(1))) void*)_gs,        \
                    (__attribute__((address_space(3))) void*)&Km[_db][j * 8 + r][0], \
                    16, 0, 0);                                                 \
            }                                                                  \
        }

        STAGEK(0);
        float Mreg = -3.4e38f, Lreg = 0.f;
        __syncthreads();   // prologue: K0 staged (drained by waitcnt+barrier)

        for (int it = 0; it <= 128; ++it) {
            if (it <= 127) {
                int cur = it & 1;
                if (it < 127) STAGEK(it + 1);

                // S^T = K*Q : 2 m-tiles x 2 k-split chains, 32 MFMA16
                f32x4 sa0 = {0.f,0.f,0.f,0.f}, sb0 = {0.f,0.f,0.f,0.f};
                f32x4 sa1 = {0.f,0.f,0.f,0.f}, sb1 = {0.f,0.f,0.f,0.f};
                __builtin_amdgcn_s_setprio(1);
#pragma unroll
                for (int kk = 0; kk < 16; kk += 2) {
                    f16x8 a00 = *reinterpret_cast<const f16x8*>(&Km[cur][li][kk * 32 + lg * 8]);
                    f16x8 a10 = *reinterpret_cast<const f16x8*>(&Km[cur][16 + li][kk * 32 + lg * 8]);
                    f16x8 a01 = *reinterpret_cast<const f16x8*>(&Km[cur][li][(kk + 1) * 32 + lg * 8]);
                    f16x8 a11 = *reinterpret_cast<const f16x8*>(&Km[cur][16 + li][(kk + 1) * 32 + lg * 8]);
                    sa0 = MFMA16(a00, qf[kk], sa0);
                    sa1 = MFMA16(a10, qf[kk], sa1);
                    sb0 = MFMA16(a01, qf[kk + 1], sb0);
                    sb1 = MFMA16(a11, qf[kk + 1], sb1);
                }
                __builtin_amdgcn_s_setprio(0);
                f32x4 s0, s1;
#pragma unroll
                for (int e = 0; e < 4; ++e) { s0[e] = sa0[e] + sb0[e]; s1[e] = sa1[e] + sb1[e]; }

                // wave-local online softmax; lane = q-row (li), 8 m-vals
                float mx = fmaxf(fmaxf(fmaxf(s0[0], s0[1]), fmaxf(s0[2], s0[3])),
                                 fmaxf(fmaxf(s1[0], s1[1]), fmaxf(s1[2], s1[3])));
                mx = fmaxf(mx, __shfl_xor(mx, 16));
                mx = fmaxf(mx, __shfl_xor(mx, 32));
                bool needR = (mx - Mreg) > 4.0f;       // defer-max THR=4
                float Mnew = needR ? mx : Mreg;
                float r = needR ? __expf(Mreg - Mnew) : 1.f;
                float p0[4], p1[4];
                float sum = 0.f;
#pragma unroll
                for (int e = 0; e < 4; ++e) {
                    p0[e] = __expf(s0[e] - Mnew);
                    p1[e] = __expf(s1[e] - Mnew);
                    sum += p0[e] + p1[e];
                }
                sum += __shfl_xor(sum, 16);
                sum += __shfl_xor(sum, 32);
                Lreg = Lreg * r + sum;
                Mreg = Mnew;

                f16x4 pk0, pk1;
#pragma unroll
                for (int e = 0; e < 4; ++e) { pk0[e] = (f16)p0[e]; pk1[e] = (f16)p1[e]; }
                *reinterpret_cast<f16x4*>(&Pl[cur][j * 16 + li][lg * 4])      = pk0;
                *reinterpret_cast<f16x4*>(&Pl[cur][j * 16 + li][16 + lg * 4]) = pk1;
                if (lg == 0) Rrow[cur][j * 16 + li] = r;
                int any = __any(needR);
                if (lane == 0) Rflag[cur][j] = any;
                if (it == 127 && lg == 0) Lrow[j * 16 + li] = Lreg;
            }
            __syncthreads();
        }
#undef STAGEK
    } else {
        // =============== PV wave (c-slice 64) ===============
        int pw = w - 4;
        int c0 = pw * 64;
        f32x4 acc[4][4];
#pragma unroll
        for (int fn = 0; fn < 4; ++fn)
#pragma unroll
            for (int fc = 0; fc < 4; ++fc)
#pragma unroll
                for (int e = 0; e < 4; ++e) acc[fn][fc][e] = 0.f;
        f16x8 vfr[4];   // V B-frags for tile it (loaded during iter it)

        __syncthreads();   // prologue barrier

        for (int it = 0; it <= 128; ++it) {
            if (it >= 1) {
                int pp = (it - 1) & 1;
                if (Rflag[pp][0] | Rflag[pp][1] | Rflag[pp][2] | Rflag[pp][3]) {
#pragma unroll
                    for (int fn = 0; fn < 4; ++fn) {
                        f32x4 rv = *reinterpret_cast<const f32x4*>(&Rrow[pp][fn * 16 + lg * 4]);
#pragma unroll
                        for (int fc = 0; fc < 4; ++fc)
#pragma unroll
                            for (int e = 0; e < 4; ++e) acc[fn][fc][e] *= rv[e];
                    }
                }
                __builtin_amdgcn_s_setprio(1);
#pragma unroll
                for (int fn = 0; fn < 4; ++fn) {
                    f16x8 af = *reinterpret_cast<const f16x8*>(&Pl[pp][fn * 16 + li][lg * 8]);
#pragma unroll
                    for (int fc = 0; fc < 4; ++fc)
                        acc[fn][fc] = MFMA16(af, vfr[fc], acc[fn][fc]);
                }
                __builtin_amdgcn_s_setprio(0);
            }
            if (it < 128) {
                // load V(it), consumed next iteration (drained at barrier)
                const f16* vs = Vb + (size_t)(c0 + li) * 4096 + it * 32 + lg * 8;
#pragma unroll
                for (int fc = 0; fc < 4; ++fc)
                    vfr[fc] = *reinterpret_cast<const f16x8*>(vs + (size_t)fc * 16 * 4096);
            }
            __syncthreads();
        }

        // epilogue: divide by L, store out[b][c][n]
        float* ob = out + (size_t)b * 512 * 4096;
#pragma unroll
        for (int fn = 0; fn < 4; ++fn) {
            f32x4 lv = *reinterpret_cast<const f32x4*>(&Lrow[fn * 16 + lg * 4]);
            f32x4 linv;
#pragma unroll
            for (int e = 0; e < 4; ++e) linv[e] = 1.f / lv[e];
#pragma unroll
            for (int fc = 0; fc < 4; ++fc) {
                int c = c0 + fc * 16 + li;
                f32x4 o4;
#pragma unroll
                for (int e = 0; e < 4; ++e) o4[e] = acc[fn][fc][e] * linv[e];
                *reinterpret_cast<f32x4*>(ob + (size_t)c * 4096 + n0 + fn * 16 + lg * 4) = o4;
            }
        }
    }
}

// ---------------------------------------------------------------------------
extern "C" void kernel_launch(void* const* d_in, const int* in_sizes, int n_in,
                              void* d_out, int out_size, void* d_ws, size_t ws_size,
                              hipStream_t stream)
{
    const float* content = (const float*)d_in[0];
    const float* style   = (const float*)d_in[1];
    const float* Wq = (const float*)d_in[2];
    const float* bq = (const float*)d_in[3];
    const float* Wk = (const float*)d_in[4];
    const float* bk = (const float*)d_in[5];
    const float* Wv = (const float*)d_in[6];
    const float* bv = (const float*)d_in[7];
    float* out = (float*)d_out;

    const size_t TEN = (size_t)4 * 4096 * 512;
    f16* Qt = (f16*)d_ws;
    f16* Kt = Qt + TEN;
    f16* Vc = Kt + TEN;
    float* mu = (float*)(Vc + TEN);
    float* rs = mu + 4096;

    hipLaunchKernelGGL(stats_kernel, dim3(4096), dim3(256), 0, stream,
                       content, style, mu, rs);
    hipLaunchKernelGGL(qkv_kernel, dim3(32, 4, 12), dim3(256), 0, stream,
                       content, style, Wq, bq, Wk, bk, Wv, bv, mu, rs, Qt, Kt, Vc);
    hipLaunchKernelGGL(attn_kernel, dim3(256), dim3(768), 0, stream,
                       Qt, Kt, Vc, out);
}

// Round 8
// 302.034 us; speedup vs baseline: 1.6791x; 1.0928x over previous
//
#include <hip/hip_runtime.h>

typedef _Float16 f16;
typedef _Float16 f16x4 __attribute__((ext_vector_type(4)));
typedef _Float16 f16x8 __attribute__((ext_vector_type(8)));
typedef float f32x4 __attribute__((ext_vector_type(4)));

#define MFMA16(a, b, c) __builtin_amdgcn_mfma_f32_16x16x32_f16(a, b, c, 0, 0, 0)

// ---------------- Kernel 1: per-(tensor,b,c) mean / inv-std ----------------
__global__ __launch_bounds__(256) void stats_kernel(
    const float* __restrict__ content, const float* __restrict__ style,
    float* __restrict__ mu, float* __restrict__ rs)
{
    int bid = blockIdx.x;            // tensor*2048 + b*512 + c
    int tensor = bid >> 11;
    int row = bid & 2047;
    const float* src = (tensor ? style : content) + (size_t)row * 4096;
    int t = threadIdx.x;
    float s = 0.f, ss = 0.f;
    for (int i = t; i < 1024; i += 256) {
        float4 v = reinterpret_cast<const float4*>(src)[i];
        s  += v.x + v.y + v.z + v.w;
        ss += v.x * v.x + v.y * v.y + v.z * v.z + v.w * v.w;
    }
    for (int off = 32; off > 0; off >>= 1) {
        s  += __shfl_down(s, off);
        ss += __shfl_down(ss, off);
    }
    __shared__ float sb[4], ssb[4];
    int wv = t >> 6;
    if ((t & 63) == 0) { sb[wv] = s; ssb[wv] = ss; }
    __syncthreads();
    if (t == 0) {
        float S  = sb[0] + sb[1] + sb[2] + sb[3];
        float SS = ssb[0] + ssb[1] + ssb[2] + ssb[3];
        float m  = S * (1.f / 4096.f);
        float var = (SS - 4096.f * m * m) * (1.f / 4095.f);
        mu[bid] = m;
        rs[bid] = rsqrtf(var + 1e-5f);
    }
}

// ---------------- Kernel 2: fused norm + 1x1-conv (Q,K,V) -----------------
// Q/K: D[o][n] = mfma(wf, xf)  -> in-lane e = consecutive o -> f16x4 stores
// V:   D[n][o] = mfma(xf, wf)  -> in-lane e = consecutive n -> f16x4 stores
__global__ __launch_bounds__(256) void qkv_kernel(
    const float* __restrict__ content, const float* __restrict__ style,
    const float* __restrict__ Wq, const float* __restrict__ bq,
    const float* __restrict__ Wk, const float* __restrict__ bk,
    const float* __restrict__ Wv, const float* __restrict__ bv,
    const float* __restrict__ mu, const float* __restrict__ rs,
    f16* __restrict__ Qt, f16* __restrict__ Kt, f16* __restrict__ Vc)
{
    int z = blockIdx.z;
    int b = z / 3, p = z % 3;
    int n0 = blockIdx.x * 128;
    int o0 = blockIdx.y * 128;
    const float* X    = (p == 0 ? content : style) + (size_t)b * 512 * 4096;
    const float* W    = (p == 0 ? Wq : (p == 1 ? Wk : Wv));
    const float* bias = (p == 0 ? bq : (p == 1 ? bk : bv));
    const float* muT = mu + (p == 0 ? 0 : 2048) + b * 512;
    const float* rsT = rs + (p == 0 ? 0 : 2048) + b * 512;
    bool norm = (p < 2);

    __shared__ __align__(16) f16 Xt[128][40];
    __shared__ __align__(16) f16 Wl[128][40];

    int t = threadIdx.x;
    int lane = t & 63, w = t >> 6;
    int wn = (w & 1) * 64, wo = (w >> 1) * 64;
    int lg = lane >> 4, li = lane & 15;

    f32x4 acc[4][4];
#pragma unroll
    for (int i = 0; i < 4; ++i)
#pragma unroll
        for (int j = 0; j < 4; ++j)
#pragma unroll
            for (int e = 0; e < 4; ++e) acc[i][j][e] = 0.f;

    for (int kk = 0; kk < 16; ++kk) {
        int c0 = kk * 32;
        __syncthreads();
#pragma unroll
        for (int r = 0; r < 4; ++r) {
            int linear = r * 256 + t;
            int c  = linear >> 5;
            int nq = linear & 31;
            float4 v = reinterpret_cast<const float4*>(X + (size_t)(c0 + c) * 4096 + n0)[nq];
            float m = 0.f, sc = 1.f;
            if (norm) { m = muT[c0 + c]; sc = rsT[c0 + c]; }
            int n = nq * 4;
            Xt[n + 0][c] = (f16)((v.x - m) * sc);
            Xt[n + 1][c] = (f16)((v.y - m) * sc);
            Xt[n + 2][c] = (f16)((v.z - m) * sc);
            Xt[n + 3][c] = (f16)((v.w - m) * sc);
        }
#pragma unroll
        for (int r = 0; r < 4; ++r) {
            int linear = r * 256 + t;
            int o  = linear >> 3;
            int cq = linear & 7;
            float4 v = reinterpret_cast<const float4*>(W + (size_t)(o0 + o) * 512 + c0)[cq];
            int c = cq * 4;
            Wl[o][c + 0] = (f16)v.x;
            Wl[o][c + 1] = (f16)v.y;
            Wl[o][c + 2] = (f16)v.z;
            Wl[o][c + 3] = (f16)v.w;
        }
        __syncthreads();

        f16x8 xf[4], wf[4];
#pragma unroll
        for (int f = 0; f < 4; ++f) {
            xf[f] = *reinterpret_cast<const f16x8*>(&Xt[wn + f * 16 + li][lg * 8]);
            wf[f] = *reinterpret_cast<const f16x8*>(&Wl[wo + f * 16 + li][lg * 8]);
        }
        if (p < 2) {            // D[o][n]: rows = o (i on wf), cols = n (j on xf)
#pragma unroll
            for (int i = 0; i < 4; ++i)
#pragma unroll
                for (int j = 0; j < 4; ++j)
                    acc[i][j] = MFMA16(wf[i], xf[j], acc[i][j]);
        } else {                // D[n][o]: rows = n (i on xf), cols = o (j on wf)
#pragma unroll
            for (int i = 0; i < 4; ++i)
#pragma unroll
                for (int j = 0; j < 4; ++j)
                    acc[i][j] = MFMA16(xf[i], wf[j], acc[i][j]);
        }
    }

    if (p < 2) {
        // lane: col = n = n0+wn+j*16+li; rows o = o0+wo+i*16+lg*4+e (e contiguous)
        f16* dst = (p == 0 ? Qt : Kt) + (size_t)b * 4096 * 512;
#pragma unroll
        for (int i = 0; i < 4; ++i) {
            int ob = o0 + wo + i * 16 + lg * 4;
            float4 bb = *reinterpret_cast<const float4*>(bias + ob);
#pragma unroll
            for (int j = 0; j < 4; ++j) {
                int n = n0 + wn + j * 16 + li;
                f16x4 pk;
                pk[0] = (f16)(acc[i][j][0] + bb.x);
                pk[1] = (f16)(acc[i][j][1] + bb.y);
                pk[2] = (f16)(acc[i][j][2] + bb.z);
                pk[3] = (f16)(acc[i][j][3] + bb.w);
                *reinterpret_cast<f16x4*>(dst + (size_t)n * 512 + ob) = pk;
            }
        }
    } else {
        // lane: col = o = o0+wo+j*16+li; rows n = n0+wn+i*16+lg*4+e (e contiguous)
#pragma unroll
        for (int j = 0; j < 4; ++j) {
            int o = o0 + wo + j * 16 + li;
            float bb = bias[o];
            f16* dst = Vc + ((size_t)b * 512 + o) * 4096;
#pragma unroll
            for (int i = 0; i < 4; ++i) {
                int n = n0 + wn + i * 16 + lg * 4;
                f16x4 pk;
#pragma unroll
                for (int e = 0; e < 4; ++e) pk[e] = (f16)(acc[i][j][e] + bb);
                *reinterpret_cast<f16x4*>(dst + n) = pk;
            }
        }
    }
}

// ---------------- Kernel 3: flash attention, 12-wave balanced, KVBLK=64 ----
// 768 thr = 12 waves; SIMD k hosts waves {k, k+4, k+8} = 1 QK + 2 PV.
// Waves 0-3: QK (16 q-rows each, wave-local softmax via swapped mfma(K,Q)).
// Waves 4-11: PV (64 c each), V in registers, P via LDS ping-pong.
// TQ=64, KVBLK=64, grid 256 (1 block/CU), ONE barrier per iteration (66 total).
__global__ __launch_bounds__(768, 3) void attn_kernel(
    const f16* __restrict__ Qt, const f16* __restrict__ Kt,
    const f16* __restrict__ Vc, float* __restrict__ out)
{
    int bid = blockIdx.x;
    int orig = (bid & 7) * 32 + (bid >> 3);   // XCD chunking
    int b = orig >> 6;
    int n0 = (orig & 63) * 64;

    int t = threadIdx.x;
    int lane = t & 63, w = t >> 6;
    int lg = lane >> 4, li = lane & 15;

    __shared__ __align__(16) f16 Km[2][64][528];   // K dbuf [m][c], 1056B rows
    __shared__ __align__(16) f16 Pl[2][64][68];    // P ping-pong [q][m], 136B rows
    __shared__ __align__(16) float Rrow[2][64];
    __shared__ __align__(16) float Lrow[64];
    __shared__ int Rflag[2][4];

    const f16* Qb = Qt + (size_t)b * 4096 * 512;
    const f16* Kb = Kt + (size_t)b * 4096 * 512;
    const f16* Vb = Vc + (size_t)b * 512 * 4096;

    if (w < 4) {
        // =============== QK / softmax wave j = w (q-rows n0+j*16..+16) =====
        int j = w;
        f16x8 qf[16];
#pragma unroll
        for (int kk = 0; kk < 16; ++kk)
            qf[kk] = *reinterpret_cast<const f16x8*>(
                Qb + (size_t)(n0 + j * 16 + li) * 512 + kk * 32 + lg * 8);

#define STAGEK(TILE)                                                           \
        {                                                                      \
            int _db = (TILE) & 1;                                              \
            _Pragma("unroll")                                                  \
            for (int r = 0; r < 16; ++r) {                                     \
                const f16* _gs = Kb + ((size_t)(TILE) * 64 + j * 16 + r) * 512 \
                                 + lane * 8;                                   \
                __builtin_amdgcn_global_load_lds(                              \
                    (const __attribute__((address_space(1))) void*)_gs,        \
                    (__attribute__((address_space(3))) void*)&Km[_db][j * 16 + r][0], \
                    16, 0, 0);                                                 \
            }                                                                  \
        }

        STAGEK(0);
        float Mreg = -3.4e38f, Lreg = 0.f;
        __syncthreads();   // prologue: K0 staged (drained by waitcnt+barrier)

        for (int it = 0; it <= 64; ++it) {
            if (it <= 63) {
                int cur = it & 1;
                if (it < 63) STAGEK(it + 1);

                // S^T = K*Q : 4 m-groups, 4 independent 16-deep chains
                f32x4 s[4];
#pragma unroll
                for (int mg = 0; mg < 4; ++mg)
#pragma unroll
                    for (int e = 0; e < 4; ++e) s[mg][e] = 0.f;
                __builtin_amdgcn_s_setprio(1);
#pragma unroll
                for (int kk = 0; kk < 16; ++kk) {
#pragma unroll
                    for (int mg = 0; mg < 4; ++mg) {
                        f16x8 kf = *reinterpret_cast<const f16x8*>(
                            &Km[cur][mg * 16 + li][kk * 32 + lg * 8]);
                        s[mg] = MFMA16(kf, qf[kk], s[mg]);
                    }
                }
                __builtin_amdgcn_s_setprio(0);

                // wave-local online softmax; lane = q-row (li), 16 m-vals
                float mx = s[0][0];
#pragma unroll
                for (int mg = 0; mg < 4; ++mg)
#pragma unroll
                    for (int e = 0; e < 4; ++e) mx = fmaxf(mx, s[mg][e]);
                mx = fmaxf(mx, __shfl_xor(mx, 16));
                mx = fmaxf(mx, __shfl_xor(mx, 32));
                bool needR = (mx - Mreg) > 4.0f;       // defer-max THR=4
                float Mnew = needR ? mx : Mreg;
                float r = needR ? __expf(Mreg - Mnew) : 1.f;
                float p[4][4];
                float sum = 0.f;
#pragma unroll
                for (int mg = 0; mg < 4; ++mg)
#pragma unroll
                    for (int e = 0; e < 4; ++e) {
                        p[mg][e] = __expf(s[mg][e] - Mnew);
                        sum += p[mg][e];
                    }
                sum += __shfl_xor(sum, 16);
                sum += __shfl_xor(sum, 32);
                Lreg = Lreg * r + sum;
                Mreg = Mnew;

                // P write: rows q = j*16+li; cols m = mg*16 + lg*4 + e
#pragma unroll
                for (int mg = 0; mg < 4; ++mg) {
                    f16x4 pk;
#pragma unroll
                    for (int e = 0; e < 4; ++e) pk[e] = (f16)p[mg][e];
                    *reinterpret_cast<f16x4*>(&Pl[cur][j * 16 + li][mg * 16 + lg * 4]) = pk;
                }
                if (lg == 0) Rrow[cur][j * 16 + li] = r;
                int any = __any(needR);
                if (lane == 0) Rflag[cur][j] = any;
                if (it == 63 && lg == 0) Lrow[j * 16 + li] = Lreg;
            }
            __syncthreads();
        }
#undef STAGEK
    } else {
        // =============== PV wave (c-slice 64) ===============
        int pw = w - 4;
        int c0 = pw * 64;
        f32x4 acc[4][4];
#pragma unroll
        for (int fn = 0; fn < 4; ++fn)
#pragma unroll
            for (int fc = 0; fc < 4; ++fc)
#pragma unroll
                for (int e = 0; e < 4; ++e) acc[fn][fc][e] = 0.f;
        f16x8 vfr[4][2];   // V B-frags [fc][ks] for tile it (loaded during iter it)

        __syncthreads();   // prologue barrier

        for (int it = 0; it <= 64; ++it) {
            if (it >= 1) {
                int pp = (it - 1) & 1;
                if (Rflag[pp][0] | Rflag[pp][1] | Rflag[pp][2] | Rflag[pp][3]) {
#pragma unroll
                    for (int fn = 0; fn < 4; ++fn) {
                        f32x4 rv = *reinterpret_cast<const f32x4*>(&Rrow[pp][fn * 16 + lg * 4]);
#pragma unroll
                        for (int fc = 0; fc < 4; ++fc)
#pragma unroll
                            for (int e = 0; e < 4; ++e) acc[fn][fc][e] *= rv[e];
                    }
                }
                __builtin_amdgcn_s_setprio(1);
#pragma unroll
                for (int fn = 0; fn < 4; ++fn) {
                    f16x8 af0 = *reinterpret_cast<const f16x8*>(&Pl[pp][fn * 16 + li][lg * 8]);
                    f16x8 af1 = *reinterpret_cast<const f16x8*>(&Pl[pp][fn * 16 + li][32 + lg * 8]);
#pragma unroll
                    for (int fc = 0; fc < 4; ++fc) {
                        acc[fn][fc] = MFMA16(af0, vfr[fc][0], acc[fn][fc]);
                        acc[fn][fc] = MFMA16(af1, vfr[fc][1], acc[fn][fc]);
                    }
                }
                __builtin_amdgcn_s_setprio(0);
            }
            if (it <= 63) {
                // load V(it), consumed next iteration (drained at barrier)
                const f16* vs = Vb + (size_t)(c0 + li) * 4096 + it * 64 + lg * 8;
#pragma unroll
                for (int fc = 0; fc < 4; ++fc) {
                    vfr[fc][0] = *reinterpret_cast<const f16x8*>(vs + (size_t)fc * 16 * 4096);
                    vfr[fc][1] = *reinterpret_cast<const f16x8*>(vs + (size_t)fc * 16 * 4096 + 32);
                }
            }
            __syncthreads();
        }

        // epilogue: divide by L, store out[b][c][n]
        float* ob = out + (size_t)b * 512 * 4096;
#pragma unroll
        for (int fn = 0; fn < 4; ++fn) {
            f32x4 lv = *reinterpret_cast<const f32x4*>(&Lrow[fn * 16 + lg * 4]);
            f32x4 linv;
#pragma unroll
            for (int e = 0; e < 4; ++e) linv[e] = 1.f / lv[e];
#pragma unroll
            for (int fc = 0; fc < 4; ++fc) {
                int c = c0 + fc * 16 + li;
                f32x4 o4;
#pragma unroll
                for (int e = 0; e < 4; ++e) o4[e] = acc[fn][fc][e] * linv[e];
                *reinterpret_cast<f32x4*>(ob + (size_t)c * 4096 + n0 + fn * 16 + lg * 4) = o4;
            }
        }
    }
}

// ---------------------------------------------------------------------------
extern "C" void kernel_launch(void* const* d_in, const int* in_sizes, int n_in,
                              void* d_out, int out_size, void* d_ws, size_t ws_size,
                              hipStream_t stream)
{
    const float* content = (const float*)d_in[0];
    const float* style   = (const float*)d_in[1];
    const float* Wq = (const float*)d_in[2];
    const float* bq = (const float*)d_in[3];
    const float* Wk = (const float*)d_in[4];
    const float* bk = (const float*)d_in[5];
    const float* Wv = (const float*)d_in[6];
    const float* bv = (const float*)d_in[7];
    float* out = (float*)d_out;

    const size_t TEN = (size_t)4 * 4096 * 512;
    f16* Qt = (f16*)d_ws;
    f16* Kt = Qt + TEN;
    f16* Vc = Kt + TEN;
    float* mu = (float*)(Vc + TEN);
    float* rs = mu + 4096;

    hipLaunchKernelGGL(stats_kernel, dim3(4096), dim3(256), 0, stream,
                       content, style, mu, rs);
    hipLaunchKernelGGL(qkv_kernel, dim3(32, 4, 12), dim3(256), 0, stream,
                       content, style, Wq, bq, Wk, bk, Wv, bv, mu, rs, Qt, Kt, Vc);
    hipLaunchKernelGGL(attn_kernel, dim3(256), dim3(768), 0, stream,
                       Qt, Kt, Vc, out);
}

// Round 9
// 250.704 us; speedup vs baseline: 2.0229x; 1.2047x over previous
//
#include <hip/hip_runtime.h>

typedef _Float16 f16;
typedef _Float16 f16x4 __attribute__((ext_vector_type(4)));
typedef _Float16 f16x8 __attribute__((ext_vector_type(8)));
typedef float f32x4 __attribute__((ext_vector_type(4)));

#define MFMA16(a, b, c) __builtin_amdgcn_mfma_f32_16x16x32_f16(a, b, c, 0, 0, 0)

// ---------------- Kernel 1: per-(tensor,b,c) mean / inv-std ----------------
__global__ __launch_bounds__(256) void stats_kernel(
    const float* __restrict__ content, const float* __restrict__ style,
    float* __restrict__ mu, float* __restrict__ rs)
{
    int bid = blockIdx.x;            // tensor*2048 + b*512 + c
    int tensor = bid >> 11;
    int row = bid & 2047;
    const float* src = (tensor ? style : content) + (size_t)row * 4096;
    int t = threadIdx.x;
    float s = 0.f, ss = 0.f;
    for (int i = t; i < 1024; i += 256) {
        float4 v = reinterpret_cast<const float4*>(src)[i];
        s  += v.x + v.y + v.z + v.w;
        ss += v.x * v.x + v.y * v.y + v.z * v.z + v.w * v.w;
    }
    for (int off = 32; off > 0; off >>= 1) {
        s  += __shfl_down(s, off);
        ss += __shfl_down(ss, off);
    }
    __shared__ float sb[4], ssb[4];
    int wv = t >> 6;
    if ((t & 63) == 0) { sb[wv] = s; ssb[wv] = ss; }
    __syncthreads();
    if (t == 0) {
        float S  = sb[0] + sb[1] + sb[2] + sb[3];
        float SS = ssb[0] + ssb[1] + ssb[2] + ssb[3];
        float m  = S * (1.f / 4096.f);
        float var = (SS - 4096.f * m * m) * (1.f / 4095.f);
        mu[bid] = m;
        rs[bid] = rsqrtf(var + 1e-5f);
    }
}

// ---------------- Kernel 1b: W -> f16 one-shot conversion ------------------
__global__ __launch_bounds__(256) void wcvt_kernel(
    const float* __restrict__ Wq, const float* __restrict__ Wk,
    const float* __restrict__ Wv, f16* __restrict__ Wh)
{
    int p = blockIdx.y;
    const float* W = (p == 0 ? Wq : (p == 1 ? Wk : Wv));
    f16* dst = Wh + (size_t)p * 262144;
    int base = blockIdx.x * 256 + threadIdx.x;       // grid.x = 32 -> 8192 threads
#pragma unroll
    for (int i = 0; i < 8; ++i) {
        int e4 = i * 8192 + base;                    // float4 index, 65536 total
        float4 v = reinterpret_cast<const float4*>(W)[e4];
        f16x4 pk;
        pk[0] = (f16)v.x; pk[1] = (f16)v.y; pk[2] = (f16)v.z; pk[3] = (f16)v.w;
        reinterpret_cast<f16x4*>(dst)[e4] = pk;
    }
}

// ---------------- Kernel 2: fused norm + 1x1-conv (Q,K,V), X-resident ------
// Block: 64 n-rows x FULL 512 o. 8 waves, wave w owns o-slice w*64..+64.
// X staged ONCE (fused norm) -> barrier-free K-loop (wf direct from L2 f16 W).
// p=0: Q -> Qt[n][o]; p=1: K -> Kt[n][o]; p=2: V -> Vc[o][n] (raw style).
__global__ __launch_bounds__(512, 3) void qkv_kernel(
    const float* __restrict__ content, const float* __restrict__ style,
    const f16* __restrict__ Wh,
    const float* __restrict__ bq, const float* __restrict__ bk,
    const float* __restrict__ bv,
    const float* __restrict__ mu, const float* __restrict__ rs,
    f16* __restrict__ Qt, f16* __restrict__ Kt, f16* __restrict__ Vc)
{
    int nb = blockIdx.x;
    int y  = blockIdx.y;
    int b = y / 3, p = y % 3;
    int n0 = nb * 64;
    const float* X    = (p == 0 ? content : style) + (size_t)b * 512 * 4096;
    const f16*   Wp   = Wh + (size_t)p * 262144;
    const float* bias = (p == 0 ? bq : (p == 1 ? bk : bv));
    const float* muT  = mu + (p == 0 ? 0 : 2048) + b * 512;
    const float* rsT  = rs + (p == 0 ? 0 : 2048) + b * 512;
    bool norm = (p < 2);

    __shared__ __align__(16) f16 Xt[64][520];   // X^T tile [n][c]

    int t = threadIdx.x;
    int lane = t & 63, w = t >> 6;
    int lg = lane >> 4, li = lane & 15;

    // ---- stage X^T once (fused norm). reads: coalesced f32 along n;
    //      writes: f16x4 along c -> 2-way banks (free). ----
#pragma unroll
    for (int i = 0; i < 16; ++i) {
        int c0 = i * 32 + w * 4;
        float x0 = X[(size_t)(c0 + 0) * 4096 + n0 + lane];
        float x1 = X[(size_t)(c0 + 1) * 4096 + n0 + lane];
        float x2 = X[(size_t)(c0 + 2) * 4096 + n0 + lane];
        float x3 = X[(size_t)(c0 + 3) * 4096 + n0 + lane];
        f16x4 pk;
        if (norm) {
            pk[0] = (f16)((x0 - muT[c0 + 0]) * rsT[c0 + 0]);
            pk[1] = (f16)((x1 - muT[c0 + 1]) * rsT[c0 + 1]);
            pk[2] = (f16)((x2 - muT[c0 + 2]) * rsT[c0 + 2]);
            pk[3] = (f16)((x3 - muT[c0 + 3]) * rsT[c0 + 3]);
        } else {
            pk[0] = (f16)x0; pk[1] = (f16)x1; pk[2] = (f16)x2; pk[3] = (f16)x3;
        }
        *reinterpret_cast<f16x4*>(&Xt[lane][c0]) = pk;
    }
    __syncthreads();

    f32x4 acc[4][4];
#pragma unroll
    for (int i = 0; i < 4; ++i)
#pragma unroll
        for (int j = 0; j < 4; ++j)
#pragma unroll
            for (int e = 0; e < 4; ++e) acc[i][j][e] = 0.f;

    // ---- barrier-free K-loop: xf from LDS, wf direct from L2 ----
    const f16* wbase = Wp + (size_t)(w * 64 + li) * 512 + lg * 8;
    for (int kk = 0; kk < 16; ++kk) {
        f16x8 xf[4], wf[4];
#pragma unroll
        for (int jn = 0; jn < 4; ++jn)
            xf[jn] = *reinterpret_cast<const f16x8*>(&Xt[jn * 16 + li][kk * 32 + lg * 8]);
#pragma unroll
        for (int io = 0; io < 4; ++io)
            wf[io] = *reinterpret_cast<const f16x8*>(wbase + (size_t)io * 16 * 512 + kk * 32);
        if (p < 2) {            // D[o][n]: acc[io][jn]
#pragma unroll
            for (int io = 0; io < 4; ++io)
#pragma unroll
                for (int jn = 0; jn < 4; ++jn)
                    acc[io][jn] = MFMA16(wf[io], xf[jn], acc[io][jn]);
        } else {                // D[n][o]: acc[jn][io]
#pragma unroll
            for (int jn = 0; jn < 4; ++jn)
#pragma unroll
                for (int io = 0; io < 4; ++io)
                    acc[jn][io] = MFMA16(xf[jn], wf[io], acc[jn][io]);
        }
    }

    // ---- epilogue: vectorized f16x4 stores (R8-proven layouts) ----
    if (p < 2) {
        // col n = n0+jn*16+li; rows o = w*64+io*16+lg*4+e (e contiguous)
        f16* dst = (p == 0 ? Qt : Kt) + (size_t)b * 4096 * 512;
#pragma unroll
        for (int io = 0; io < 4; ++io) {
            int ob = w * 64 + io * 16 + lg * 4;
            float4 bb = *reinterpret_cast<const float4*>(bias + ob);
#pragma unroll
            for (int jn = 0; jn < 4; ++jn) {
                int n = n0 + jn * 16 + li;
                f16x4 pk;
                pk[0] = (f16)(acc[io][jn][0] + bb.x);
                pk[1] = (f16)(acc[io][jn][1] + bb.y);
                pk[2] = (f16)(acc[io][jn][2] + bb.z);
                pk[3] = (f16)(acc[io][jn][3] + bb.w);
                *reinterpret_cast<f16x4*>(dst + (size_t)n * 512 + ob) = pk;
            }
        }
    } else {
        // col o = w*64+io*16+li; rows n = n0+jn*16+lg*4+e (e contiguous)
#pragma unroll
        for (int io = 0; io < 4; ++io) {
            int o = w * 64 + io * 16 + li;
            float bb = bias[o];
            f16* dst = Vc + ((size_t)b * 512 + o) * 4096;
#pragma unroll
            for (int jn = 0; jn < 4; ++jn) {
                int n = n0 + jn * 16 + lg * 4;
                f16x4 pk;
#pragma unroll
                for (int e = 0; e < 4; ++e) pk[e] = (f16)(acc[jn][io][e] + bb);
                *reinterpret_cast<f16x4*>(dst + n) = pk;
            }
        }
    }
}

// ---------------- Kernel 3: flash attention, 12-wave balanced, KVBLK=64 ----
// (unchanged from R8: 183 us, 0 bank conflicts)
__global__ __launch_bounds__(768, 3) void attn_kernel(
    const f16* __restrict__ Qt, const f16* __restrict__ Kt,
    const f16* __restrict__ Vc, float* __restrict__ out)
{
    int bid = blockIdx.x;
    int orig = (bid & 7) * 32 + (bid >> 3);   // XCD chunking
    int b = orig >> 6;
    int n0 = (orig & 63) * 64;

    int t = threadIdx.x;
    int lane = t & 63, w = t >> 6;
    int lg = lane >> 4, li = lane & 15;

    __shared__ __align__(16) f16 Km[2][64][528];   // K dbuf [m][c]
    __shared__ __align__(16) f16 Pl[2][64][68];    // P ping-pong [q][m]
    __shared__ __align__(16) float Rrow[2][64];
    __shared__ __align__(16) float Lrow[64];
    __shared__ int Rflag[2][4];

    const f16* Qb = Qt + (size_t)b * 4096 * 512;
    const f16* Kb = Kt + (size_t)b * 4096 * 512;
    const f16* Vb = Vc + (size_t)b * 512 * 4096;

    if (w < 4) {
        int j = w;
        f16x8 qf[16];
#pragma unroll
        for (int kk = 0; kk < 16; ++kk)
            qf[kk] = *reinterpret_cast<const f16x8*>(
                Qb + (size_t)(n0 + j * 16 + li) * 512 + kk * 32 + lg * 8);

#define STAGEK(TILE)                                                           \
        {                                                                      \
            int _db = (TILE) & 1;                                              \
            _Pragma("unroll")                                                  \
            for (int r = 0; r < 16; ++r) {                                     \
                const f16* _gs = Kb + ((size_t)(TILE) * 64 + j * 16 + r) * 512 \
                                 + lane * 8;                                   \
                __builtin_amdgcn_global_load_lds(                              \
                    (const __attribute__((address_space(1))) void*)_gs,        \
                    (__attribute__((address_space(3))) void*)&Km[_db][j * 16 + r][0], \
                    16, 0, 0);                                                 \
            }                                                                  \
        }

        STAGEK(0);
        float Mreg = -3.4e38f, Lreg = 0.f;
        __syncthreads();

        for (int it = 0; it <= 64; ++it) {
            if (it <= 63) {
                int cur = it & 1;
                if (it < 63) STAGEK(it + 1);

                f32x4 s[4];
#pragma unroll
                for (int mg = 0; mg < 4; ++mg)
#pragma unroll
                    for (int e = 0; e < 4; ++e) s[mg][e] = 0.f;
                __builtin_amdgcn_s_setprio(1);
#pragma unroll
                for (int kk = 0; kk < 16; ++kk) {
#pragma unroll
                    for (int mg = 0; mg < 4; ++mg) {
                        f16x8 kf = *reinterpret_cast<const f16x8*>(
                            &Km[cur][mg * 16 + li][kk * 32 + lg * 8]);
                        s[mg] = MFMA16(kf, qf[kk], s[mg]);
                    }
                }
                __builtin_amdgcn_s_setprio(0);

                float mx = s[0][0];
#pragma unroll
                for (int mg = 0; mg < 4; ++mg)
#pragma unroll
                    for (int e = 0; e < 4; ++e) mx = fmaxf(mx, s[mg][e]);
                mx = fmaxf(mx, __shfl_xor(mx, 16));
                mx = fmaxf(mx, __shfl_xor(mx, 32));
                bool needR = (mx - Mreg) > 4.0f;       // defer-max THR=4
                float Mnew = needR ? mx : Mreg;
                float r = needR ? __expf(Mreg - Mnew) : 1.f;
                float p[4][4];
                float sum = 0.f;
#pragma unroll
                for (int mg = 0; mg < 4; ++mg)
#pragma unroll
                    for (int e = 0; e < 4; ++e) {
                        p[mg][e] = __expf(s[mg][e] - Mnew);
                        sum += p[mg][e];
                    }
                sum += __shfl_xor(sum, 16);
                sum += __shfl_xor(sum, 32);
                Lreg = Lreg * r + sum;
                Mreg = Mnew;

#pragma unroll
                for (int mg = 0; mg < 4; ++mg) {
                    f16x4 pk;
#pragma unroll
                    for (int e = 0; e < 4; ++e) pk[e] = (f16)p[mg][e];
                    *reinterpret_cast<f16x4*>(&Pl[cur][j * 16 + li][mg * 16 + lg * 4]) = pk;
                }
                if (lg == 0) Rrow[cur][j * 16 + li] = r;
                int any = __any(needR);
                if (lane == 0) Rflag[cur][j] = any;
                if (it == 63 && lg == 0) Lrow[j * 16 + li] = Lreg;
            }
            __syncthreads();
        }
#undef STAGEK
    } else {
        int pw = w - 4;
        int c0 = pw * 64;
        f32x4 acc[4][4];
#pragma unroll
        for (int fn = 0; fn < 4; ++fn)
#pragma unroll
            for (int fc = 0; fc < 4; ++fc)
#pragma unroll
                for (int e = 0; e < 4; ++e) acc[fn][fc][e] = 0.f;
        f16x8 vfr[4][2];

        __syncthreads();

        for (int it = 0; it <= 64; ++it) {
            if (it >= 1) {
                int pp = (it - 1) & 1;
                if (Rflag[pp][0] | Rflag[pp][1] | Rflag[pp][2] | Rflag[pp][3]) {
#pragma unroll
                    for (int fn = 0; fn < 4; ++fn) {
                        f32x4 rv = *reinterpret_cast<const f32x4*>(&Rrow[pp][fn * 16 + lg * 4]);
#pragma unroll
                        for (int fc = 0; fc < 4; ++fc)
#pragma unroll
                            for (int e = 0; e < 4; ++e) acc[fn][fc][e] *= rv[e];
                    }
                }
                __builtin_amdgcn_s_setprio(1);
#pragma unroll
                for (int fn = 0; fn < 4; ++fn) {
                    f16x8 af0 = *reinterpret_cast<const f16x8*>(&Pl[pp][fn * 16 + li][lg * 8]);
                    f16x8 af1 = *reinterpret_cast<const f16x8*>(&Pl[pp][fn * 16 + li][32 + lg * 8]);
#pragma unroll
                    for (int fc = 0; fc < 4; ++fc) {
                        acc[fn][fc] = MFMA16(af0, vfr[fc][0], acc[fn][fc]);
                        acc[fn][fc] = MFMA16(af1, vfr[fc][1], acc[fn][fc]);
                    }
                }
                __builtin_amdgcn_s_setprio(0);
            }
            if (it <= 63) {
                const f16* vs = Vb + (size_t)(c0 + li) * 4096 + it * 64 + lg * 8;
#pragma unroll
                for (int fc = 0; fc < 4; ++fc) {
                    vfr[fc][0] = *reinterpret_cast<const f16x8*>(vs + (size_t)fc * 16 * 4096);
                    vfr[fc][1] = *reinterpret_cast<const f16x8*>(vs + (size_t)fc * 16 * 4096 + 32);
                }
            }
            __syncthreads();
        }

        float* ob = out + (size_t)b * 512 * 4096;
#pragma unroll
        for (int fn = 0; fn < 4; ++fn) {
            f32x4 lv = *reinterpret_cast<const f32x4*>(&Lrow[fn * 16 + lg * 4]);
            f32x4 linv;
#pragma unroll
            for (int e = 0; e < 4; ++e) linv[e] = 1.f / lv[e];
#pragma unroll
            for (int fc = 0; fc < 4; ++fc) {
                int c = c0 + fc * 16 + li;
                f32x4 o4;
#pragma unroll
                for (int e = 0; e < 4; ++e) o4[e] = acc[fn][fc][e] * linv[e];
                *reinterpret_cast<f32x4*>(ob + (size_t)c * 4096 + n0 + fn * 16 + lg * 4) = o4;
            }
        }
    }
}

// ---------------------------------------------------------------------------
extern "C" void kernel_launch(void* const* d_in, const int* in_sizes, int n_in,
                              void* d_out, int out_size, void* d_ws, size_t ws_size,
                              hipStream_t stream)
{
    const float* content = (const float*)d_in[0];
    const float* style   = (const float*)d_in[1];
    const float* Wq = (const float*)d_in[2];
    const float* bq = (const float*)d_in[3];
    const float* Wk = (const float*)d_in[4];
    const float* bk = (const float*)d_in[5];
    const float* Wv = (const float*)d_in[6];
    const float* bv = (const float*)d_in[7];
    float* out = (float*)d_out;

    const size_t TEN = (size_t)4 * 4096 * 512;
    f16* Qt = (f16*)d_ws;
    f16* Kt = Qt + TEN;
    f16* Vc = Kt + TEN;
    float* mu = (float*)(Vc + TEN);
    float* rs = mu + 4096;
    f16* Wh = (f16*)(rs + 4096);             // 3 x 512 x 512 f16 = 1.5 MB

    hipLaunchKernelGGL(stats_kernel, dim3(4096), dim3(256), 0, stream,
                       content, style, mu, rs);
    hipLaunchKernelGGL(wcvt_kernel, dim3(32, 3), dim3(256), 0, stream,
                       Wq, Wk, Wv, Wh);
    hipLaunchKernelGGL(qkv_kernel, dim3(64, 12), dim3(512), 0, stream,
                       content, style, Wh, bq, bk, bv, mu, rs, Qt, Kt, Vc);
    hipLaunchKernelGGL(attn_kernel, dim3(256), dim3(768), 0, stream,
                       Qt, Kt, Vc, out);
}